// Round 6
// baseline (960.228 us; speedup 1.0000x reference)
//
#include <hip/hip_runtime.h>
#include <math.h>

// Problem constants
#define L_SEQ 2048
#define DM    768
#define DI    1536          // d_inner
#define DTR   48            // dt_rank
#define DST   16            // d_state
#define XDW   80            // dt_rank + 2*d_state
#define NCH   64            // scan chunks
#define LC    32            // L_SEQ / NCH
#define XPS   8             // x_proj K-splits
#define XPK   (DI / XPS)    // 192
#define NBLK  448           // persistent grid; 2 blocks/CU guaranteed resident

typedef short bf16x8 __attribute__((ext_vector_type(8)));
typedef float f32x4  __attribute__((ext_vector_type(4)));

__device__ __forceinline__ float silu_f(float x) {
    return x / (1.0f + __expf(-x));
}

__device__ __forceinline__ short f2bf(float x) {
    union { float f; unsigned u; } v; v.f = x;
    unsigned r = v.u + 0x7fff + ((v.u >> 16) & 1);
    return (short)(r >> 16);
}

// ---------------------------------------------------------------------------
// Grid barrier v2. Round-4 version thrashed L2 (per-thread __threadfence x2 +
// ACQUIRE in the poll loop = continuous XCD-L2 invalidation by 448 spinners).
// v2: thread-0 only; RELEASE on arrival (one L2 writeback per block);
// RELAXED poll + s_sleep (no cache ops); single ACQUIRE after exit (one
// invalidate per block per barrier). __syncthreads() before = each wave
// drains vmcnt (its global writes reach L2); release pushes them down.
// ---------------------------------------------------------------------------
__device__ __forceinline__ void grid_barrier(unsigned* bar) {
    __syncthreads();
    if (threadIdx.x == 0) {
        unsigned g = __hip_atomic_load(&bar[32], __ATOMIC_RELAXED, __HIP_MEMORY_SCOPE_AGENT);
        unsigned a = __hip_atomic_fetch_add(&bar[0], 1u, __ATOMIC_RELEASE, __HIP_MEMORY_SCOPE_AGENT);
        if (a == (unsigned)(gridDim.x - 1)) {
            __hip_atomic_store(&bar[0], 0u, __ATOMIC_RELAXED, __HIP_MEMORY_SCOPE_AGENT);
            __hip_atomic_store(&bar[32], g + 1u, __ATOMIC_RELEASE, __HIP_MEMORY_SCOPE_AGENT);
        } else {
            while (__hip_atomic_load(&bar[32], __ATOMIC_RELAXED, __HIP_MEMORY_SCOPE_AGENT) == g)
                __builtin_amdgcn_s_sleep(8);
        }
        // single acquire: invalidate this CU's L1 + XCD L2 once
        (void)__hip_atomic_load(&bar[0], __ATOMIC_ACQUIRE, __HIP_MEMORY_SCOPE_AGENT);
    }
    __syncthreads();
}

// ---------------------------------------------------------------------------
// bf16 MFMA GEMM phase: C[M,N] (+)= A[M,K] @ Bt[N,K]^T, 128x128 tiles,
// grid-stride over tiles. smem: As 8KB + Bs 8KB.
// ---------------------------------------------------------------------------
__device__ void gemm128(const short* __restrict__ A, const short* __restrict__ Bt,
                        float* __restrict__ C, int M, int N, int K, int accum,
                        char* smem)
{
    short* As = (short*)smem;
    short* Bs = (short*)(smem + 8192);
    int tid = threadIdx.x, lane = tid & 63, w = tid >> 6;
    int wr = w >> 1, wc = w & 1;
    int ntx = N >> 7;
    int ntiles = (M >> 7) * ntx;

    for (int t = blockIdx.x; t < ntiles; t += gridDim.x) {
        int brow = (t / ntx) << 7, bcol = (t % ntx) << 7;
        f32x4 acc[4][4] = {};
        for (int k0 = 0; k0 < K; k0 += 32) {
            __syncthreads();
            #pragma unroll
            for (int i = 0; i < 2; i++) {
                int c = tid + i * 256;
                int r = c >> 2, q = c & 3;
                const short* ga = A  + (size_t)(brow + r) * K + k0 + q * 8;
                const short* gb = Bt + (size_t)(bcol + r) * K + k0 + q * 8;
                __builtin_amdgcn_global_load_lds(
                    (const __attribute__((address_space(1))) void*)ga,
                    (__attribute__((address_space(3))) void*)&As[r * 32 + q * 8],
                    16, 0, 0);
                __builtin_amdgcn_global_load_lds(
                    (const __attribute__((address_space(1))) void*)gb,
                    (__attribute__((address_space(3))) void*)&Bs[r * 32 + q * 8],
                    16, 0, 0);
            }
            __syncthreads();

            bf16x8 af[4], bfv[4];
            int kh = (lane >> 4) * 8;
            int ml = lane & 15;
            #pragma unroll
            for (int tt = 0; tt < 4; tt++) {
                af[tt]  = *(const bf16x8*)&As[(wr * 64 + tt * 16 + ml) * 32 + kh];
                bfv[tt] = *(const bf16x8*)&Bs[(wc * 64 + tt * 16 + ml) * 32 + kh];
            }
            #pragma unroll
            for (int mt = 0; mt < 4; mt++)
                #pragma unroll
                for (int nt = 0; nt < 4; nt++)
                    acc[mt][nt] = __builtin_amdgcn_mfma_f32_16x16x32_bf16(
                        af[mt], bfv[nt], acc[mt][nt], 0, 0, 0);
        }
        int r0 = (lane >> 4) * 4, c0 = lane & 15;
        #pragma unroll
        for (int mt = 0; mt < 4; mt++)
            #pragma unroll
            for (int nt = 0; nt < 4; nt++)
                #pragma unroll
                for (int reg = 0; reg < 4; reg++) {
                    int row = brow + wr * 64 + mt * 16 + r0 + reg;
                    int col = bcol + wc * 64 + nt * 16 + c0;
                    float v = acc[mt][nt][reg];
                    if (accum) C[(size_t)row * N + col] += v;
                    else       C[(size_t)row * N + col] = v;
                }
        __syncthreads();
    }
}

// ---------------------------------------------------------------------------
// out_proj: 128x64 tiles, C += A@Bt^T. Wave w: rows w*32..+31, 64 cols.
// smem: As 8KB + Bs 4KB.
// ---------------------------------------------------------------------------
__device__ void gemm_n64_acc(const short* __restrict__ A, const short* __restrict__ Bt,
                             float* __restrict__ C, int M, int N, int K, char* smem)
{
    short* As = (short*)smem;
    short* Bs = (short*)(smem + 8192);
    int tid = threadIdx.x, lane = tid & 63, w = tid >> 6;
    int ntx = N >> 6;
    int ntiles = (M >> 7) * ntx;

    for (int t = blockIdx.x; t < ntiles; t += gridDim.x) {
        int brow = (t / ntx) << 7, bcol = (t % ntx) << 6;
        f32x4 acc[2][4] = {};
        for (int k0 = 0; k0 < K; k0 += 32) {
            __syncthreads();
            #pragma unroll
            for (int i = 0; i < 2; i++) {
                int c = tid + i * 256;
                int r = c >> 2, q = c & 3;
                const short* ga = A + (size_t)(brow + r) * K + k0 + q * 8;
                __builtin_amdgcn_global_load_lds(
                    (const __attribute__((address_space(1))) void*)ga,
                    (__attribute__((address_space(3))) void*)&As[r * 32 + q * 8],
                    16, 0, 0);
            }
            {
                int r = tid >> 2, q = tid & 3;
                const short* gb = Bt + (size_t)(bcol + r) * K + k0 + q * 8;
                __builtin_amdgcn_global_load_lds(
                    (const __attribute__((address_space(1))) void*)gb,
                    (__attribute__((address_space(3))) void*)&Bs[r * 32 + q * 8],
                    16, 0, 0);
            }
            __syncthreads();

            bf16x8 af[2], bfv[4];
            int kh = (lane >> 4) * 8;
            int ml = lane & 15;
            #pragma unroll
            for (int mt = 0; mt < 2; mt++)
                af[mt] = *(const bf16x8*)&As[(w * 32 + mt * 16 + ml) * 32 + kh];
            #pragma unroll
            for (int nt = 0; nt < 4; nt++)
                bfv[nt] = *(const bf16x8*)&Bs[(nt * 16 + ml) * 32 + kh];
            #pragma unroll
            for (int mt = 0; mt < 2; mt++)
                #pragma unroll
                for (int nt = 0; nt < 4; nt++)
                    acc[mt][nt] = __builtin_amdgcn_mfma_f32_16x16x32_bf16(
                        af[mt], bfv[nt], acc[mt][nt], 0, 0, 0);
        }
        int r0 = (lane >> 4) * 4, c0 = lane & 15;
        #pragma unroll
        for (int mt = 0; mt < 2; mt++)
            #pragma unroll
            for (int nt = 0; nt < 4; nt++)
                #pragma unroll
                for (int reg = 0; reg < 4; reg++) {
                    int row = brow + w * 32 + mt * 16 + r0 + reg;
                    int col = bcol + nt * 16 + c0;
                    C[(size_t)row * N + col] += acc[mt][nt][reg];
                }
        __syncthreads();
    }
}

// ---------------------------------------------------------------------------
// Mega-kernel: whole 2-layer forward; phases identical to round-5 kernels.
// ---------------------------------------------------------------------------
__global__ __launch_bounds__(256, 2) void mamba_mega(
    const int*   __restrict__ ids,
    const float* __restrict__ emb,
    const float* __restrict__ norm_w,
    const float* __restrict__ in_proj_w,
    const float* __restrict__ conv_w,
    const float* __restrict__ conv_b,
    const float* __restrict__ x_proj_w,
    const float* __restrict__ dt_proj_w,
    const float* __restrict__ dt_proj_b,
    const float* __restrict__ A_log,
    const float* __restrict__ Dp,
    const float* __restrict__ out_proj_w,
    float* __restrict__ x,
    unsigned* bar,
    float* __restrict__ xz,    float* __restrict__ xr,
    float* __restrict__ delta, float* __restrict__ xpart,
    float* __restrict__ xdbl_bc,
    float* __restrict__ aprod, float* __restrict__ hfin, float* __restrict__ hin,
    short* __restrict__ xn_bf, short* __restrict__ y2_bf, short* __restrict__ xr_bf,
    short* __restrict__ ipw_t, short* __restrict__ opw_t, short* __restrict__ xpw_t)
{
    __shared__ __align__(16) char smem[16384];
    const int tid = threadIdx.x;

    // ===== phase 0: weight transposes + embedding =====
    {
        int lx = tid & 31, ly = tid >> 5;
        float* tile = (float*)smem;              // [32][33]
        for (int t = blockIdx.x; t < 7200; t += gridDim.x) {
            int layer = t >= 3600;
            int tt = t - layer * 3600;
            const float* src; short* dst; int K, N, txc;
            if (tt < 2304) {
                src = in_proj_w + (size_t)layer * DM * 2 * DI;
                dst = ipw_t + (size_t)layer * 2 * DI * DM;
                K = DM; N = 2 * DI; txc = 96;
            } else if (tt < 3456) {
                tt -= 2304;
                src = out_proj_w + (size_t)layer * DI * DM;
                dst = opw_t + (size_t)layer * DM * DI;
                K = DI; N = DM; txc = 24;
            } else {
                tt -= 3456;
                src = x_proj_w + (size_t)layer * DI * XDW;
                dst = xpw_t + (size_t)layer * XDW * DI;
                K = DI; N = XDW; txc = 3;
            }
            int n0 = (tt % txc) * 32, k0 = (tt / txc) * 32;
            __syncthreads();
            #pragma unroll
            for (int i = 0; i < 4; i++) {
                int nn = n0 + lx;
                tile[(ly + i * 8) * 33 + lx] =
                    (nn < N) ? src[(size_t)(k0 + ly + i * 8) * N + nn] : 0.f;
            }
            __syncthreads();
            #pragma unroll
            for (int i = 0; i < 4; i++) {
                int nn = n0 + ly + i * 8;
                if (nn < N)
                    dst[(size_t)nn * K + k0 + lx] = f2bf(tile[lx * 33 + ly + i * 8]);
            }
        }
        for (int idx = blockIdx.x * 256 + tid; idx < L_SEQ * (DM / 4); idx += gridDim.x * 256) {
            int row = idx / (DM / 4), col = idx % (DM / 4);
            ((float4*)x)[idx] = ((const float4*)emb)[(size_t)ids[row] * (DM / 4) + col];
        }
    }
    grid_barrier(bar);

    for (int layer = 0; layer < 2; layer++) {
        const float* nw   = norm_w    + (size_t)layer * DM;
        const float* cw   = conv_w    + (size_t)layer * DI * 4;
        const float* cb   = conv_b    + (size_t)layer * DI;
        const float* dpw  = dt_proj_w + (size_t)layer * DTR * DI;
        const float* dpb  = dt_proj_b + (size_t)layer * DI;
        const float* al   = A_log     + (size_t)layer * DI * DST;
        const float* dpp  = Dp        + (size_t)layer * DI;
        const short* ipwt = ipw_t + (size_t)layer * 2 * DI * DM;
        const short* opwt = opw_t + (size_t)layer * DM * DI;
        const short* xpwt = xpw_t + (size_t)layer * XDW * DI;

        // ===== rmsnorm -> xn_bf =====
        {
            float* wred = (float*)smem;
            int wave = tid >> 6, lane = tid & 63;
            for (int row = blockIdx.x; row < L_SEQ; row += gridDim.x) {
                const float* xrow = x + (size_t)row * DM;
                float s = 0.f;
                for (int i = tid; i < DM; i += 256) { float v = xrow[i]; s += v * v; }
                #pragma unroll
                for (int off = 32; off > 0; off >>= 1) s += __shfl_down(s, off, 64);
                if (lane == 0) wred[wave] = s;
                __syncthreads();
                float tot = wred[0] + wred[1] + wred[2] + wred[3];
                float rs = rsqrtf(tot / (float)DM + 1e-5f);
                for (int i = tid; i < DM; i += 256)
                    xn_bf[(size_t)row * DM + i] = f2bf(xrow[i] * rs * nw[i]);
                __syncthreads();
            }
        }
        grid_barrier(bar);

        // ===== in_proj =====
        gemm128(xn_bf, ipwt, xz, L_SEQ, 2 * DI, DM, 0, smem);
        grid_barrier(bar);

        // ===== conv + silu =====
        for (int idx = blockIdx.x * 256 + tid; idx < L_SEQ * DI; idx += gridDim.x * 256) {
            int l = idx / DI, c = idx % DI;
            float4 wc4 = ((const float4*)cw)[c];
            const float* col = xz + c;
            float acc = cb[c];
            if (l >= 3) {
                acc += wc4.x * col[(size_t)(l - 3) * (2 * DI)]
                     + wc4.y * col[(size_t)(l - 2) * (2 * DI)]
                     + wc4.z * col[(size_t)(l - 1) * (2 * DI)]
                     + wc4.w * col[(size_t)l * (2 * DI)];
            } else {
                const float wv[4] = {wc4.x, wc4.y, wc4.z, wc4.w};
                for (int k = 0; k < 4; k++) {
                    int ls = l - 3 + k;
                    if (ls >= 0) acc += wv[k] * col[(size_t)ls * (2 * DI)];
                }
            }
            float v = silu_f(acc);
            xr[idx] = v;
            xr_bf[idx] = f2bf(v);
        }
        grid_barrier(bar);

        // ===== x_proj split-K =====
        {
            int w = tid >> 6, lane = tid & 63;
            int ml = lane & 15, kh = (lane >> 4) * 8;
            for (int j = blockIdx.x; j < 32 * XPS; j += gridDim.x) {
                int rg = j & 31, sp = j >> 5;
                int r0 = rg * 64 + w * 16;
                int k0 = sp * XPK;
                f32x4 acc5[5] = {};
                for (int ks = 0; ks < XPK; ks += 32) {
                    bf16x8 a = *(const bf16x8*)&xr_bf[(size_t)(r0 + ml) * DI + k0 + ks + kh];
                    #pragma unroll
                    for (int t5 = 0; t5 < 5; t5++) {
                        bf16x8 b = *(const bf16x8*)&xpwt[(size_t)(t5 * 16 + ml) * DI + k0 + ks + kh];
                        acc5[t5] = __builtin_amdgcn_mfma_f32_16x16x32_bf16(a, b, acc5[t5], 0, 0, 0);
                    }
                }
                float* po = xpart + (size_t)sp * L_SEQ * XDW;
                int rb = r0 + (lane >> 4) * 4;
                #pragma unroll
                for (int t5 = 0; t5 < 5; t5++)
                    #pragma unroll
                    for (int reg = 0; reg < 4; reg++)
                        po[(size_t)(rb + reg) * XDW + t5 * 16 + ml] = acc5[t5][reg];
            }
        }
        grid_barrier(bar);

        // ===== dt_proj fused (reduce partials + K=48 GEMM + softplus) =====
        {
            float* As_f = (float*)smem;             // [16][68]
            float* Bs_f = (float*)(smem + 4352);
            int ty = tid >> 4, tx = tid & 15;
            for (int t = blockIdx.x; t < 768; t += gridDim.x) {
                int bcol = (t % 24) * 64;
                int brow = (t / 24) * 64;
                float acc[4][4] = {};
                for (int k0 = 0; k0 < 48; k0 += 16) {
                    __syncthreads();
                    #pragma unroll
                    for (int i = 0; i < 4; i++) {
                        int idx = tid + i * 256;
                        int m = idx >> 4, k = idx & 15;
                        float s = 0.f;
                        #pragma unroll
                        for (int p = 0; p < XPS; p++)
                            s += xpart[((size_t)p * L_SEQ + brow + m) * XDW + k0 + k];
                        As_f[k * 68 + m] = s;
                    }
                    #pragma unroll
                    for (int i = 0; i < 4; i++) {
                        int idx = tid + i * 256;
                        int k = idx >> 6, n = idx & 63;
                        Bs_f[k * 68 + n] = dpw[(size_t)(k0 + k) * DI + bcol + n];
                    }
                    __syncthreads();
                    #pragma unroll
                    for (int k = 0; k < 16; k++) {
                        float4 av = *(const float4*)&As_f[k * 68 + ty * 4];
                        float4 bv = *(const float4*)&Bs_f[k * 68 + tx * 4];
                        float a4[4] = {av.x, av.y, av.z, av.w};
                        float b4[4] = {bv.x, bv.y, bv.z, bv.w};
                        #pragma unroll
                        for (int i = 0; i < 4; i++)
                            #pragma unroll
                            for (int jj = 0; jj < 4; jj++)
                                acc[i][jj] += a4[i] * b4[jj];
                    }
                }
                #pragma unroll
                for (int i = 0; i < 4; i++) {
                    int row = brow + ty * 4 + i;
                    #pragma unroll
                    for (int jj = 0; jj < 4; jj++) {
                        int col = bcol + tx * 4 + jj;
                        float v = acc[i][jj] + dpb[col];
                        delta[(size_t)row * DI + col] = (v > 20.f) ? v : log1pf(__expf(v));
                    }
                }
                if (t % 24 == 0) {
                    for (int e = tid; e < 64 * 32; e += 256) {
                        int r = e >> 5, cc = e & 31;
                        float s = 0.f;
                        #pragma unroll
                        for (int p = 0; p < XPS; p++)
                            s += xpart[((size_t)p * L_SEQ + brow + r) * XDW + DTR + cc];
                        xdbl_bc[(size_t)(brow + r) * 32 + cc] = s;
                    }
                }
                __syncthreads();
            }
        }
        grid_barrier(bar);

        // ===== scan pass A =====
        for (int j = blockIdx.x; j < NCH * 6; j += gridDim.x) {
            int dg = j % 6, c = j / 6;
            int d = dg * 256 + tid;
            float Aloc[DST], h[DST], P[DST];
            #pragma unroll
            for (int n4 = 0; n4 < DST; n4 += 4) {
                float4 alv = *(const float4*)&al[(size_t)d * DST + n4];
                Aloc[n4 + 0] = -__expf(alv.x); Aloc[n4 + 1] = -__expf(alv.y);
                Aloc[n4 + 2] = -__expf(alv.z); Aloc[n4 + 3] = -__expf(alv.w);
            }
            #pragma unroll
            for (int n = 0; n < DST; n++) { h[n] = 0.f; P[n] = 1.f; }
            int l0 = c * LC;
            for (int l = l0; l < l0 + LC; l++) {
                float dl = delta[(size_t)l * DI + d];
                float ul = xr[(size_t)l * DI + d];
                float du = dl * ul;
                float Bv[DST];
                const float4* B4 = (const float4*)(xdbl_bc + (size_t)l * 32);
                *(float4*)&Bv[0] = B4[0]; *(float4*)&Bv[4]  = B4[1];
                *(float4*)&Bv[8] = B4[2]; *(float4*)&Bv[12] = B4[3];
                #pragma unroll
                for (int n = 0; n < DST; n++) {
                    float da = __expf(dl * Aloc[n]);
                    h[n] = h[n] * da + du * Bv[n];
                    P[n] *= da;
                }
            }
            size_t base = ((size_t)c * DI + d) * DST;
            #pragma unroll
            for (int n = 0; n < DST; n += 4) {
                *(float4*)&aprod[base + n] = *(float4*)&P[n];
                *(float4*)&hfin[base + n]  = *(float4*)&h[n];
            }
        }
        grid_barrier(bar);

        // ===== scan pass B: sequential carry (coalesced) =====
        for (int idx = blockIdx.x * 256 + tid; idx < DI * DST; idx += gridDim.x * 256) {
            float cur = 0.f;
            for (int c = 0; c < NCH; c++) {
                size_t o = (size_t)c * DI * DST + idx;
                hin[o] = cur;
                cur = hfin[o] + aprod[o] * cur;
            }
        }
        grid_barrier(bar);

        // ===== scan pass C =====
        for (int j = blockIdx.x; j < NCH * 6; j += gridDim.x) {
            int dg = j % 6, c = j / 6;
            int d = dg * 256 + tid;
            float Aloc[DST], h[DST];
            #pragma unroll
            for (int n4 = 0; n4 < DST; n4 += 4) {
                float4 alv = *(const float4*)&al[(size_t)d * DST + n4];
                Aloc[n4 + 0] = -__expf(alv.x); Aloc[n4 + 1] = -__expf(alv.y);
                Aloc[n4 + 2] = -__expf(alv.z); Aloc[n4 + 3] = -__expf(alv.w);
            }
            size_t base = ((size_t)c * DI + d) * DST;
            #pragma unroll
            for (int n = 0; n < DST; n += 4)
                *(float4*)&h[n] = *(const float4*)&hin[base + n];
            float Dd = dpp[d];
            int l0 = c * LC;
            for (int l = l0; l < l0 + LC; l++) {
                float dl = delta[(size_t)l * DI + d];
                float ul = xr[(size_t)l * DI + d];
                float du = dl * ul;
                float Bv[DST], Cv[DST];
                const float4* B4 = (const float4*)(xdbl_bc + (size_t)l * 32);
                const float4* C4 = (const float4*)(xdbl_bc + (size_t)l * 32 + 16);
                *(float4*)&Bv[0] = B4[0]; *(float4*)&Bv[4]  = B4[1];
                *(float4*)&Bv[8] = B4[2]; *(float4*)&Bv[12] = B4[3];
                *(float4*)&Cv[0] = C4[0]; *(float4*)&Cv[4]  = C4[1];
                *(float4*)&Cv[8] = C4[2]; *(float4*)&Cv[12] = C4[3];
                float y = 0.f;
                #pragma unroll
                for (int n = 0; n < DST; n++) {
                    float da = __expf(dl * Aloc[n]);
                    h[n] = h[n] * da + du * Bv[n];
                    y += h[n] * Cv[n];
                }
                y += ul * Dd;
                float r = xz[(size_t)l * (2 * DI) + DI + d];
                y2_bf[(size_t)l * DI + d] = f2bf(y * silu_f(r));
            }
        }
        grid_barrier(bar);

        // ===== out_proj: x += y2 @ W =====
        gemm_n64_acc(y2_bf, opwt, x, L_SEQ, DM, DI, smem);
        if (layer == 0) grid_barrier(bar);
    }
}

// ---------------------------------------------------------------------------
// Host launch: 2 dispatches (barrier init memset + mega-kernel)
// ---------------------------------------------------------------------------
extern "C" void kernel_launch(void* const* d_in, const int* in_sizes, int n_in,
                              void* d_out, int out_size, void* d_ws, size_t ws_size,
                              hipStream_t stream)
{
    const int*   ids       = (const int*)d_in[0];
    const float* emb       = (const float*)d_in[1];
    const float* norm_w    = (const float*)d_in[2];
    const float* in_proj_w = (const float*)d_in[3];
    const float* conv_w    = (const float*)d_in[4];
    const float* conv_b    = (const float*)d_in[5];
    const float* x_proj_w  = (const float*)d_in[6];
    const float* dt_proj_w = (const float*)d_in[7];
    const float* dt_proj_b = (const float*)d_in[8];
    const float* A_log     = (const float*)d_in[9];
    const float* Dp        = (const float*)d_in[10];
    const float* out_proj_w= (const float*)d_in[11];

    float* x = (float*)d_out;

    char* wsb = (char*)d_ws;
    unsigned* bar = (unsigned*)wsb;  wsb += 256;
    auto alloc_f = [&](size_t n) { float* p = (float*)wsb; wsb += n * 4; return p; };
    auto alloc_s = [&](size_t n) { short* p = (short*)wsb; wsb += ((n * 2 + 15) & ~15ull); return p; };

    float* xz      = alloc_f((size_t)L_SEQ * 2 * DI);
    float* xr      = alloc_f((size_t)L_SEQ * DI);
    float* delta   = alloc_f((size_t)L_SEQ * DI);
    float* xpart   = alloc_f((size_t)XPS * L_SEQ * XDW);
    float* xdbl_bc = alloc_f((size_t)L_SEQ * 32);
    float* aprod   = alloc_f((size_t)NCH * DI * DST);
    float* hfin    = alloc_f((size_t)NCH * DI * DST);
    float* hin     = alloc_f((size_t)NCH * DI * DST);
    short* xn_bf   = alloc_s((size_t)L_SEQ * DM);
    short* y2_bf   = alloc_s((size_t)L_SEQ * DI);
    short* xr_bf   = alloc_s((size_t)L_SEQ * DI);
    short* ipw_t   = alloc_s((size_t)2 * 2 * DI * DM);
    short* opw_t   = alloc_s((size_t)2 * DM * DI);
    short* xpw_t   = alloc_s((size_t)2 * XDW * DI);

    hipMemsetAsync(bar, 0, 256, stream);

    mamba_mega<<<NBLK, 256, 0, stream>>>(
        ids, emb, norm_w, in_proj_w, conv_w, conv_b, x_proj_w,
        dt_proj_w, dt_proj_b, A_log, Dp, out_proj_w,
        x, bar,
        xz, xr, delta, xpart, xdbl_bc, aprod, hfin, hin,
        xn_bf, y2_bf, xr_bf, ipw_t, opw_t, xpw_t);
}

// Round 7
// 513.561 us; speedup vs baseline: 1.8697x; 1.8697x over previous
//
#include <hip/hip_runtime.h>
#include <math.h>

// Problem constants
#define L_SEQ 2048
#define DM    768
#define DI    1536          // d_inner
#define DTR   48            // dt_rank
#define DST   16            // d_state
#define XDW   80            // dt_rank + 2*d_state
#define NCH   64            // scan chunks
#define LC    32            // L_SEQ / NCH
#define XPS   8             // x_proj K-splits
#define XPK   (DI / XPS)    // 192
#define XPAD  200           // LDS row pitch (shorts) for conv/xproj tile

typedef short bf16x8 __attribute__((ext_vector_type(8)));
typedef float f32x4  __attribute__((ext_vector_type(4)));

__device__ __forceinline__ float silu_f(float x) {
    return x / (1.0f + __expf(-x));
}

__device__ __forceinline__ short f2bf(float x) {
    union { float f; unsigned u; } v; v.f = x;
    unsigned r = v.u + 0x7fff + ((v.u >> 16) & 1);
    return (short)(r >> 16);
}

__device__ __forceinline__ float bf2f(short s) {
    union { float f; unsigned u; } v;
    v.u = ((unsigned)(unsigned short)s) << 16;
    return v.f;
}

// ---------------------------------------------------------------------------
// Prep: per-row embed + layer-0 RMSNorm, then grid-stride weight transposes.
// Grid: 2048 blocks x 256.
// ---------------------------------------------------------------------------
__global__ __launch_bounds__(256) void prep_kernel(
    const int*   __restrict__ ids,
    const float* __restrict__ emb,
    const float* __restrict__ norm_w,      // layer 0 row
    const float* __restrict__ in_proj_w,
    const float* __restrict__ out_proj_w,
    const float* __restrict__ x_proj_w,
    float* __restrict__ x,
    short* __restrict__ xn_bf,
    short* __restrict__ ipw_t, short* __restrict__ opw_t, short* __restrict__ xpw_t)
{
    __shared__ float tile[32 * 33];
    __shared__ float wred[4];
    const int tid = threadIdx.x;

    // ---- embed + rmsnorm for row = blockIdx.x ----
    {
        int row = blockIdx.x;
        int tok = ids[row];
        float4 v4 = make_float4(0.f, 0.f, 0.f, 0.f);
        if (tid < DM / 4) {
            v4 = ((const float4*)emb)[(size_t)tok * (DM / 4) + tid];
            ((float4*)x)[(size_t)row * (DM / 4) + tid] = v4;
        }
        float s = v4.x * v4.x + v4.y * v4.y + v4.z * v4.z + v4.w * v4.w;
        #pragma unroll
        for (int off = 32; off > 0; off >>= 1) s += __shfl_down(s, off, 64);
        int wave = tid >> 6, lane = tid & 63;
        if (lane == 0) wred[wave] = s;
        __syncthreads();
        float tot = wred[0] + wred[1] + wred[2] + wred[3];
        float rs = rsqrtf(tot / (float)DM + 1e-5f);
        if (tid < DM / 4) {
            int i = tid * 4;
            short4 o;
            o.x = f2bf(v4.x * rs * norm_w[i + 0]);
            o.y = f2bf(v4.y * rs * norm_w[i + 1]);
            o.z = f2bf(v4.z * rs * norm_w[i + 2]);
            o.w = f2bf(v4.w * rs * norm_w[i + 3]);
            ((short4*)xn_bf)[(size_t)row * (DM / 4) + tid] = o;
        }
        __syncthreads();
    }

    // ---- weight transposes, grid-stride over 7200 32x32 tiles ----
    int lx = tid & 31, ly = tid >> 5;
    for (int t = blockIdx.x; t < 7200; t += gridDim.x) {
        int layer = t >= 3600;
        int tt = t - layer * 3600;
        const float* src; short* dst; int K, N, txc;
        if (tt < 2304) {
            src = in_proj_w + (size_t)layer * DM * 2 * DI;
            dst = ipw_t + (size_t)layer * 2 * DI * DM;
            K = DM; N = 2 * DI; txc = 96;
        } else if (tt < 3456) {
            tt -= 2304;
            src = out_proj_w + (size_t)layer * DI * DM;
            dst = opw_t + (size_t)layer * DM * DI;
            K = DI; N = DM; txc = 24;
        } else {
            tt -= 3456;
            src = x_proj_w + (size_t)layer * DI * XDW;
            dst = xpw_t + (size_t)layer * XDW * DI;
            K = DI; N = XDW; txc = 3;
        }
        int n0 = (tt % txc) * 32, k0 = (tt / txc) * 32;
        __syncthreads();
        #pragma unroll
        for (int i = 0; i < 4; i++) {
            int nn = n0 + lx;
            tile[(ly + i * 8) * 33 + lx] =
                (nn < N) ? src[(size_t)(k0 + ly + i * 8) * N + nn] : 0.f;
        }
        __syncthreads();
        #pragma unroll
        for (int i = 0; i < 4; i++) {
            int nn = n0 + ly + i * 8;
            if (nn < N)
                dst[(size_t)nn * K + k0 + lx] = f2bf(tile[lx * 33 + ly + i * 8]);
        }
    }
}

// ---------------------------------------------------------------------------
// RMSNorm -> bf16 (layer 1 only)
// ---------------------------------------------------------------------------
__global__ __launch_bounds__(256) void rmsnorm_kernel(
    const float* __restrict__ x, const float* __restrict__ w,
    short* __restrict__ out)
{
    int row = blockIdx.x;
    const float* xr = x + (size_t)row * DM;
    float s = 0.f;
    for (int i = threadIdx.x; i < DM; i += 256) { float v = xr[i]; s += v * v; }
    #pragma unroll
    for (int off = 32; off > 0; off >>= 1) s += __shfl_down(s, off, 64);
    __shared__ float ws[4];
    int wave = threadIdx.x >> 6, lane = threadIdx.x & 63;
    if (lane == 0) ws[wave] = s;
    __syncthreads();
    float tot = ws[0] + ws[1] + ws[2] + ws[3];
    float rs = rsqrtf(tot / (float)DM + 1e-5f);
    for (int i = threadIdx.x; i < DM; i += 256)
        out[(size_t)row * DM + i] = f2bf(xr[i] * rs * w[i]);
}

// ---------------------------------------------------------------------------
// bf16 MFMA GEMM: C[M,N] = A[M,K] @ Bt[N,K]^T, 128x128 tiles (in_proj)
// ---------------------------------------------------------------------------
__global__ __launch_bounds__(256) void gemm_bf16_bt(
    const short* __restrict__ A, const short* __restrict__ Bt,
    float* __restrict__ C, int M, int N, int K)
{
    __shared__ short As[128 * 32];
    __shared__ short Bs[128 * 32];
    int tid = threadIdx.x, lane = tid & 63, w = tid >> 6;
    int wr = w >> 1, wc = w & 1;
    int brow = blockIdx.y * 128, bcol = blockIdx.x * 128;

    f32x4 acc[4][4] = {};

    for (int k0 = 0; k0 < K; k0 += 32) {
        #pragma unroll
        for (int i = 0; i < 2; i++) {
            int c = tid + i * 256;
            int r = c >> 2, q = c & 3;
            const short* ga = A  + (size_t)(brow + r) * K + k0 + q * 8;
            const short* gb = Bt + (size_t)(bcol + r) * K + k0 + q * 8;
            __builtin_amdgcn_global_load_lds(
                (const __attribute__((address_space(1))) void*)ga,
                (__attribute__((address_space(3))) void*)&As[r * 32 + q * 8],
                16, 0, 0);
            __builtin_amdgcn_global_load_lds(
                (const __attribute__((address_space(1))) void*)gb,
                (__attribute__((address_space(3))) void*)&Bs[r * 32 + q * 8],
                16, 0, 0);
        }
        __syncthreads();

        bf16x8 af[4], bfv[4];
        int kh = (lane >> 4) * 8;
        int ml = lane & 15;
        #pragma unroll
        for (int t = 0; t < 4; t++) {
            af[t]  = *(const bf16x8*)&As[(wr * 64 + t * 16 + ml) * 32 + kh];
            bfv[t] = *(const bf16x8*)&Bs[(wc * 64 + t * 16 + ml) * 32 + kh];
        }
        #pragma unroll
        for (int mt = 0; mt < 4; mt++)
            #pragma unroll
            for (int nt = 0; nt < 4; nt++)
                acc[mt][nt] = __builtin_amdgcn_mfma_f32_16x16x32_bf16(
                    af[mt], bfv[nt], acc[mt][nt], 0, 0, 0);
        __syncthreads();
    }

    int r0 = (lane >> 4) * 4, c0 = lane & 15;
    #pragma unroll
    for (int mt = 0; mt < 4; mt++)
        #pragma unroll
        for (int nt = 0; nt < 4; nt++)
            #pragma unroll
            for (int reg = 0; reg < 4; reg++) {
                int row = brow + wr * 64 + mt * 16 + r0 + reg;
                int col = bcol + wc * 64 + nt * 16 + c0;
                C[(size_t)row * N + col] = acc[mt][nt][reg];
            }
}

// ---------------------------------------------------------------------------
// out_proj: 128x64 tiles, C += A@Bt^T
// ---------------------------------------------------------------------------
__global__ __launch_bounds__(256) void gemm_bf16_bt_n64(
    const short* __restrict__ A, const short* __restrict__ Bt,
    float* __restrict__ C, int M, int N, int K)
{
    __shared__ short As[128 * 32];
    __shared__ short Bs[64 * 32];
    int tid = threadIdx.x, lane = tid & 63, w = tid >> 6;
    int brow = blockIdx.y * 128, bcol = blockIdx.x * 64;

    f32x4 acc[2][4] = {};

    for (int k0 = 0; k0 < K; k0 += 32) {
        #pragma unroll
        for (int i = 0; i < 2; i++) {
            int c = tid + i * 256;
            int r = c >> 2, q = c & 3;
            const short* ga = A + (size_t)(brow + r) * K + k0 + q * 8;
            __builtin_amdgcn_global_load_lds(
                (const __attribute__((address_space(1))) void*)ga,
                (__attribute__((address_space(3))) void*)&As[r * 32 + q * 8],
                16, 0, 0);
        }
        {
            int r = tid >> 2, q = tid & 3;
            const short* gb = Bt + (size_t)(bcol + r) * K + k0 + q * 8;
            __builtin_amdgcn_global_load_lds(
                (const __attribute__((address_space(1))) void*)gb,
                (__attribute__((address_space(3))) void*)&Bs[r * 32 + q * 8],
                16, 0, 0);
        }
        __syncthreads();

        bf16x8 af[2], bfv[4];
        int kh = (lane >> 4) * 8;
        int ml = lane & 15;
        #pragma unroll
        for (int mt = 0; mt < 2; mt++)
            af[mt] = *(const bf16x8*)&As[(w * 32 + mt * 16 + ml) * 32 + kh];
        #pragma unroll
        for (int nt = 0; nt < 4; nt++)
            bfv[nt] = *(const bf16x8*)&Bs[(nt * 16 + ml) * 32 + kh];
        #pragma unroll
        for (int mt = 0; mt < 2; mt++)
            #pragma unroll
            for (int nt = 0; nt < 4; nt++)
                acc[mt][nt] = __builtin_amdgcn_mfma_f32_16x16x32_bf16(
                    af[mt], bfv[nt], acc[mt][nt], 0, 0, 0);
        __syncthreads();
    }

    int r0 = (lane >> 4) * 4, c0 = lane & 15;
    #pragma unroll
    for (int mt = 0; mt < 2; mt++)
        #pragma unroll
        for (int nt = 0; nt < 4; nt++)
            #pragma unroll
            for (int reg = 0; reg < 4; reg++) {
                int row = brow + w * 32 + mt * 16 + r0 + reg;
                int col = bcol + nt * 16 + c0;
                C[(size_t)row * N + col] += acc[mt][nt][reg];
            }
}

// ---------------------------------------------------------------------------
// Fused conv+silu + x_proj split-K MFMA.
// Grid (32, XPS): block = 64 rows (l) x 192 channels tile of xr.
// Computes conv+silu for its tile (disjoint coverage), writes xr_bf global,
// keeps bf16 tile in LDS (pitch 200 shorts => 2-way bank aliasing only),
// then MFMA: part[sp][L][80] partial over its K-slice.
// ---------------------------------------------------------------------------
__global__ __launch_bounds__(256) void convxproj_kernel(
    const float* __restrict__ xz, const float* __restrict__ cw,
    const float* __restrict__ cb, const short* __restrict__ xpw_t,
    short* __restrict__ xr_bf, float* __restrict__ part)
{
    __shared__ __align__(16) short lds[64 * XPAD];
    const int tid = threadIdx.x;
    int rg = blockIdx.x;            // row group (64 rows)
    int sp = blockIdx.y;            // K-split
    int l0 = rg * 64;
    int k0 = sp * XPK;

    // conv + silu for the 64x192 tile
    for (int e = tid; e < 64 * XPK; e += 256) {
        int ll = e / XPK, cc = e % XPK;
        int l = l0 + ll, c = k0 + cc;
        float4 wc4 = ((const float4*)cw)[c];
        const float* col = xz + c;
        float acc = cb[c];
        if (l >= 3) {
            acc += wc4.x * col[(size_t)(l - 3) * (2 * DI)]
                 + wc4.y * col[(size_t)(l - 2) * (2 * DI)]
                 + wc4.z * col[(size_t)(l - 1) * (2 * DI)]
                 + wc4.w * col[(size_t)l * (2 * DI)];
        } else {
            const float wv[4] = {wc4.x, wc4.y, wc4.z, wc4.w};
            for (int k = 0; k < 4; k++) {
                int ls = l - 3 + k;
                if (ls >= 0) acc += wv[k] * col[(size_t)ls * (2 * DI)];
            }
        }
        short b = f2bf(silu_f(acc));
        lds[ll * XPAD + cc] = b;
        xr_bf[(size_t)l * DI + c] = b;
    }
    __syncthreads();

    // x_proj partial MFMA from LDS
    int w = tid >> 6, lane = tid & 63;
    int ml = lane & 15, kh = (lane >> 4) * 8;
    int rl = w * 16 + ml;           // local row 0..63
    f32x4 acc5[5] = {};
    for (int ks = 0; ks < XPK; ks += 32) {
        bf16x8 a = *(const bf16x8*)&lds[rl * XPAD + ks + kh];
        #pragma unroll
        for (int t5 = 0; t5 < 5; t5++) {
            bf16x8 b = *(const bf16x8*)&xpw_t[(size_t)(t5 * 16 + ml) * DI + k0 + ks + kh];
            acc5[t5] = __builtin_amdgcn_mfma_f32_16x16x32_bf16(a, b, acc5[t5], 0, 0, 0);
        }
    }
    float* po = part + (size_t)sp * L_SEQ * XDW;
    int rb = l0 + w * 16 + (lane >> 4) * 4;
    #pragma unroll
    for (int t5 = 0; t5 < 5; t5++)
        #pragma unroll
        for (int reg = 0; reg < 4; reg++)
            po[(size_t)(rb + reg) * XDW + t5 * 16 + ml] = acc5[t5][reg];
}

// ---------------------------------------------------------------------------
// dt_proj fused: reduce xpart partials + fp32 GEMM(K=48) + softplus -> delta.
// Blocks with blockIdx.x%24==0 also reduce B/C cols -> xdbl_bc[L][32].
// ---------------------------------------------------------------------------
__global__ __launch_bounds__(256) void dtproj_fused(
    const float* __restrict__ xpart, const float* __restrict__ dpw,
    const float* __restrict__ dpb, float* __restrict__ delta,
    float* __restrict__ xdbl_bc)
{
    __shared__ __align__(16) float As_f[16 * 68];
    __shared__ __align__(16) float Bs_f[16 * 68];
    int tid = threadIdx.x;
    int ty = tid >> 4, tx = tid & 15;
    int t = blockIdx.x;
    int bcol = (t % 24) * 64;
    int brow = (t / 24) * 64;

    float acc[4][4] = {};
    for (int k0 = 0; k0 < 48; k0 += 16) {
        __syncthreads();
        #pragma unroll
        for (int i = 0; i < 4; i++) {
            int idx = tid + i * 256;
            int m = idx >> 4, k = idx & 15;
            float s = 0.f;
            #pragma unroll
            for (int p = 0; p < XPS; p++)
                s += xpart[((size_t)p * L_SEQ + brow + m) * XDW + k0 + k];
            As_f[k * 68 + m] = s;
        }
        #pragma unroll
        for (int i = 0; i < 4; i++) {
            int idx = tid + i * 256;
            int k = idx >> 6, n = idx & 63;
            Bs_f[k * 68 + n] = dpw[(size_t)(k0 + k) * DI + bcol + n];
        }
        __syncthreads();
        #pragma unroll
        for (int k = 0; k < 16; k++) {
            float4 av = *(const float4*)&As_f[k * 68 + ty * 4];
            float4 bv = *(const float4*)&Bs_f[k * 68 + tx * 4];
            float a4[4] = {av.x, av.y, av.z, av.w};
            float b4[4] = {bv.x, bv.y, bv.z, bv.w};
            #pragma unroll
            for (int i = 0; i < 4; i++)
                #pragma unroll
                for (int jj = 0; jj < 4; jj++)
                    acc[i][jj] += a4[i] * b4[jj];
        }
    }
    #pragma unroll
    for (int i = 0; i < 4; i++) {
        int row = brow + ty * 4 + i;
        #pragma unroll
        for (int jj = 0; jj < 4; jj++) {
            int col = bcol + tx * 4 + jj;
            float v = acc[i][jj] + dpb[col];
            delta[(size_t)row * DI + col] = (v > 20.f) ? v : log1pf(__expf(v));
        }
    }
    if (t % 24 == 0) {
        for (int e = tid; e < 64 * 32; e += 256) {
            int r = e >> 5, cc = e & 31;
            float s = 0.f;
            #pragma unroll
            for (int p = 0; p < XPS; p++)
                s += xpart[((size_t)p * L_SEQ + brow + r) * XDW + DTR + cc];
            xdbl_bc[(size_t)(brow + r) * 32 + cc] = s;
        }
    }
}

// ---------------------------------------------------------------------------
// Scan pass A (u from xr_bf)
// ---------------------------------------------------------------------------
__global__ __launch_bounds__(256) void scan_passA(
    const float* __restrict__ delta, const short* __restrict__ xr_bf,
    const float* __restrict__ xdbl_bc, const float* __restrict__ al,
    float* __restrict__ aprod, float* __restrict__ hfin)
{
    int d = blockIdx.x * 256 + threadIdx.x;
    int c = blockIdx.y;

    float Aloc[DST], h[DST], P[DST];
    #pragma unroll
    for (int n4 = 0; n4 < DST; n4 += 4) {
        float4 alv = *(const float4*)&al[(size_t)d * DST + n4];
        Aloc[n4 + 0] = -__expf(alv.x); Aloc[n4 + 1] = -__expf(alv.y);
        Aloc[n4 + 2] = -__expf(alv.z); Aloc[n4 + 3] = -__expf(alv.w);
    }
    #pragma unroll
    for (int n = 0; n < DST; n++) { h[n] = 0.f; P[n] = 1.f; }

    int l0 = c * LC;
    for (int l = l0; l < l0 + LC; l++) {
        float dl = delta[(size_t)l * DI + d];
        float ul = bf2f(xr_bf[(size_t)l * DI + d]);
        float du = dl * ul;
        float Bv[DST];
        const float4* B4 = (const float4*)(xdbl_bc + (size_t)l * 32);
        *(float4*)&Bv[0] = B4[0]; *(float4*)&Bv[4]  = B4[1];
        *(float4*)&Bv[8] = B4[2]; *(float4*)&Bv[12] = B4[3];
        #pragma unroll
        for (int n = 0; n < DST; n++) {
            float da = __expf(dl * Aloc[n]);
            h[n] = h[n] * da + du * Bv[n];
            P[n] *= da;
        }
    }
    size_t base = ((size_t)c * DI + d) * DST;
    #pragma unroll
    for (int n = 0; n < DST; n += 4) {
        *(float4*)&aprod[base + n] = *(float4*)&P[n];
        *(float4*)&hfin[base + n]  = *(float4*)&h[n];
    }
}

// ---------------------------------------------------------------------------
// Pass B: sequential carry over chunks (coalesced)
// ---------------------------------------------------------------------------
__global__ __launch_bounds__(256) void scan_passB(
    const float* __restrict__ aprod, const float* __restrict__ hfin,
    float* __restrict__ hin)
{
    int idx = blockIdx.x * 256 + threadIdx.x;
    if (idx >= DI * DST) return;
    float cur = 0.f;
    for (int c = 0; c < NCH; c++) {
        size_t o = (size_t)c * DI * DST + idx;
        hin[o] = cur;
        cur = hfin[o] + aprod[o] * cur;
    }
}

// ---------------------------------------------------------------------------
// Pass C: replay with carry; fuse y, D, gating -> y2_bf
// ---------------------------------------------------------------------------
__global__ __launch_bounds__(256) void scan_passC(
    const float* __restrict__ delta, const short* __restrict__ xr_bf,
    const float* __restrict__ xdbl_bc, const float* __restrict__ al,
    const float* __restrict__ dpp, const float* __restrict__ hin,
    const float* __restrict__ xz, short* __restrict__ y2)
{
    int d = blockIdx.x * 256 + threadIdx.x;
    int c = blockIdx.y;

    float Aloc[DST], h[DST];
    #pragma unroll
    for (int n4 = 0; n4 < DST; n4 += 4) {
        float4 alv = *(const float4*)&al[(size_t)d * DST + n4];
        Aloc[n4 + 0] = -__expf(alv.x); Aloc[n4 + 1] = -__expf(alv.y);
        Aloc[n4 + 2] = -__expf(alv.z); Aloc[n4 + 3] = -__expf(alv.w);
    }
    size_t base = ((size_t)c * DI + d) * DST;
    #pragma unroll
    for (int n = 0; n < DST; n += 4)
        *(float4*)&h[n] = *(const float4*)&hin[base + n];
    float Dd = dpp[d];

    int l0 = c * LC;
    for (int l = l0; l < l0 + LC; l++) {
        float dl = delta[(size_t)l * DI + d];
        float ul = bf2f(xr_bf[(size_t)l * DI + d]);
        float du = dl * ul;
        float Bv[DST], Cv[DST];
        const float4* B4 = (const float4*)(xdbl_bc + (size_t)l * 32);
        const float4* C4 = (const float4*)(xdbl_bc + (size_t)l * 32 + 16);
        *(float4*)&Bv[0] = B4[0]; *(float4*)&Bv[4]  = B4[1];
        *(float4*)&Bv[8] = B4[2]; *(float4*)&Bv[12] = B4[3];
        *(float4*)&Cv[0] = C4[0]; *(float4*)&Cv[4]  = C4[1];
        *(float4*)&Cv[8] = C4[2]; *(float4*)&Cv[12] = C4[3];
        float y = 0.f;
        #pragma unroll
        for (int n = 0; n < DST; n++) {
            float da = __expf(dl * Aloc[n]);
            h[n] = h[n] * da + du * Bv[n];
            y += h[n] * Cv[n];
        }
        y += ul * Dd;
        float r = xz[(size_t)l * (2 * DI) + DI + d];
        y2[(size_t)l * DI + d] = f2bf(y * silu_f(r));
    }
}

// ---------------------------------------------------------------------------
// Host launch: 16 dispatches
// ---------------------------------------------------------------------------
extern "C" void kernel_launch(void* const* d_in, const int* in_sizes, int n_in,
                              void* d_out, int out_size, void* d_ws, size_t ws_size,
                              hipStream_t stream)
{
    const int*   ids       = (const int*)d_in[0];
    const float* emb       = (const float*)d_in[1];
    const float* norm_w    = (const float*)d_in[2];
    const float* in_proj_w = (const float*)d_in[3];
    const float* conv_w    = (const float*)d_in[4];
    const float* conv_b    = (const float*)d_in[5];
    const float* x_proj_w  = (const float*)d_in[6];
    const float* dt_proj_w = (const float*)d_in[7];
    const float* dt_proj_b = (const float*)d_in[8];
    const float* A_log     = (const float*)d_in[9];
    const float* Dp        = (const float*)d_in[10];
    const float* out_proj_w= (const float*)d_in[11];

    float* x = (float*)d_out;

    char* wsb = (char*)d_ws;
    auto alloc_f = [&](size_t n) { float* p = (float*)wsb; wsb += n * 4; return p; };
    auto alloc_s = [&](size_t n) { short* p = (short*)wsb; wsb += ((n * 2 + 15) & ~15ull); return p; };

    float* xz      = alloc_f((size_t)L_SEQ * 2 * DI);
    float* delta   = alloc_f((size_t)L_SEQ * DI);
    float* xpart   = alloc_f((size_t)XPS * L_SEQ * XDW);
    float* xdbl_bc = alloc_f((size_t)L_SEQ * 32);
    float* aprod   = alloc_f((size_t)NCH * DI * DST);
    float* hfin    = alloc_f((size_t)NCH * DI * DST);
    float* hin     = alloc_f((size_t)NCH * DI * DST);
    short* xn_bf   = alloc_s((size_t)L_SEQ * DM);
    short* y2_bf   = alloc_s((size_t)L_SEQ * DI);
    short* xr_bf   = alloc_s((size_t)L_SEQ * DI);
    short* ipw_t   = alloc_s((size_t)2 * 2 * DI * DM);
    short* opw_t   = alloc_s((size_t)2 * DM * DI);
    short* xpw_t   = alloc_s((size_t)2 * XDW * DI);

    // 1 dispatch: embed + rmsnorm(L0) + all weight transposes
    prep_kernel<<<L_SEQ, 256, 0, stream>>>(
        ids, emb, norm_w, in_proj_w, out_proj_w, x_proj_w,
        x, xn_bf, ipw_t, opw_t, xpw_t);

    for (int layer = 0; layer < 2; layer++) {
        const float* nw   = norm_w    + (size_t)layer * DM;
        const float* cw   = conv_w    + (size_t)layer * DI * 4;
        const float* cb   = conv_b    + (size_t)layer * DI;
        const float* dpw  = dt_proj_w + (size_t)layer * DTR * DI;
        const float* dpb  = dt_proj_b + (size_t)layer * DI;
        const float* al   = A_log     + (size_t)layer * DI * DST;
        const float* dpp  = Dp        + (size_t)layer * DI;
        const short* ipwt = ipw_t + (size_t)layer * 2 * DI * DM;
        const short* opwt = opw_t + (size_t)layer * DM * DI;
        const short* xpwt = xpw_t + (size_t)layer * XDW * DI;

        if (layer == 1)
            rmsnorm_kernel<<<L_SEQ, 256, 0, stream>>>(x, nw, xn_bf);

        gemm_bf16_bt<<<dim3(2 * DI / 128, L_SEQ / 128), 256, 0, stream>>>(
            xn_bf, ipwt, xz, L_SEQ, 2 * DI, DM);

        convxproj_kernel<<<dim3(32, XPS), 256, 0, stream>>>(
            xz, cw, cb, xpwt, xr_bf, xpart);

        dtproj_fused<<<768, 256, 0, stream>>>(xpart, dpw, dpb, delta, xdbl_bc);

        scan_passA<<<dim3(DI / 256, NCH), 256, 0, stream>>>(
            delta, xr_bf, xdbl_bc, al, aprod, hfin);
        scan_passB<<<(DI * DST) / 256, 256, 0, stream>>>(aprod, hfin, hin);
        scan_passC<<<dim3(DI / 256, NCH), 256, 0, stream>>>(
            delta, xr_bf, xdbl_bc, al, dpp, hin, xz, y2_bf);

        gemm_bf16_bt_n64<<<dim3(DM / 64, L_SEQ / 128), 256, 0, stream>>>(
            y2_bf, opwt, x, L_SEQ, DM, DI);
    }
}

// Round 8
// 468.354 us; speedup vs baseline: 2.0502x; 1.0965x over previous
//
#include <hip/hip_runtime.h>
#include <math.h>

// Problem constants
#define L_SEQ 2048
#define DM    768
#define DI    1536          // d_inner
#define DTR   48            // dt_rank
#define DST   16            // d_state
#define XDW   80            // dt_rank + 2*d_state
#define NCH   64            // scan chunks
#define LC    32            // L_SEQ / NCH
#define XPS   8             // x_proj K-splits
#define XPK   (DI / XPS)    // 192

typedef short bf16x8 __attribute__((ext_vector_type(8)));
typedef float f32x4  __attribute__((ext_vector_type(4)));

__device__ __forceinline__ float silu_f(float x) {
    return x / (1.0f + __expf(-x));
}

__device__ __forceinline__ short f2bf(float x) {
    union { float f; unsigned u; } v; v.f = x;
    unsigned r = v.u + 0x7fff + ((v.u >> 16) & 1);
    return (short)(r >> 16);
}

__device__ __forceinline__ float bf2f(short s) {
    union { float f; unsigned u; } v;
    v.u = ((unsigned)(unsigned short)s) << 16;
    return v.f;
}

// ---------------------------------------------------------------------------
// Prep: per-row embed + layer-0 RMSNorm, then grid-stride weight transposes.
// Grid: 2048 blocks x 256.  (verified accuracy-neutral in r7)
// ---------------------------------------------------------------------------
__global__ __launch_bounds__(256) void prep_kernel(
    const int*   __restrict__ ids,
    const float* __restrict__ emb,
    const float* __restrict__ norm_w,      // layer 0 row
    const float* __restrict__ in_proj_w,
    const float* __restrict__ out_proj_w,
    const float* __restrict__ x_proj_w,
    float* __restrict__ x,
    short* __restrict__ xn_bf,
    short* __restrict__ ipw_t, short* __restrict__ opw_t, short* __restrict__ xpw_t)
{
    __shared__ float tile[32 * 33];
    __shared__ float wred[4];
    const int tid = threadIdx.x;

    // ---- embed + rmsnorm for row = blockIdx.x ----
    {
        int row = blockIdx.x;
        int tok = ids[row];
        float4 v4 = make_float4(0.f, 0.f, 0.f, 0.f);
        if (tid < DM / 4) {
            v4 = ((const float4*)emb)[(size_t)tok * (DM / 4) + tid];
            ((float4*)x)[(size_t)row * (DM / 4) + tid] = v4;
        }
        float s = v4.x * v4.x + v4.y * v4.y + v4.z * v4.z + v4.w * v4.w;
        #pragma unroll
        for (int off = 32; off > 0; off >>= 1) s += __shfl_down(s, off, 64);
        int wave = tid >> 6, lane = tid & 63;
        if (lane == 0) wred[wave] = s;
        __syncthreads();
        float tot = wred[0] + wred[1] + wred[2] + wred[3];
        float rs = rsqrtf(tot / (float)DM + 1e-5f);
        if (tid < DM / 4) {
            int i = tid * 4;
            short4 o;
            o.x = f2bf(v4.x * rs * norm_w[i + 0]);
            o.y = f2bf(v4.y * rs * norm_w[i + 1]);
            o.z = f2bf(v4.z * rs * norm_w[i + 2]);
            o.w = f2bf(v4.w * rs * norm_w[i + 3]);
            ((short4*)xn_bf)[(size_t)row * (DM / 4) + tid] = o;
        }
        __syncthreads();
    }

    // ---- weight transposes, grid-stride over 7200 32x32 tiles ----
    int lx = tid & 31, ly = tid >> 5;
    for (int t = blockIdx.x; t < 7200; t += gridDim.x) {
        int layer = t >= 3600;
        int tt = t - layer * 3600;
        const float* src; short* dst; int K, N, txc;
        if (tt < 2304) {
            src = in_proj_w + (size_t)layer * DM * 2 * DI;
            dst = ipw_t + (size_t)layer * 2 * DI * DM;
            K = DM; N = 2 * DI; txc = 96;
        } else if (tt < 3456) {
            tt -= 2304;
            src = out_proj_w + (size_t)layer * DI * DM;
            dst = opw_t + (size_t)layer * DM * DI;
            K = DI; N = DM; txc = 24;
        } else {
            tt -= 3456;
            src = x_proj_w + (size_t)layer * DI * XDW;
            dst = xpw_t + (size_t)layer * XDW * DI;
            K = DI; N = XDW; txc = 3;
        }
        int n0 = (tt % txc) * 32, k0 = (tt / txc) * 32;
        __syncthreads();
        #pragma unroll
        for (int i = 0; i < 4; i++) {
            int nn = n0 + lx;
            tile[(ly + i * 8) * 33 + lx] =
                (nn < N) ? src[(size_t)(k0 + ly + i * 8) * N + nn] : 0.f;
        }
        __syncthreads();
        #pragma unroll
        for (int i = 0; i < 4; i++) {
            int nn = n0 + ly + i * 8;
            if (nn < N)
                dst[(size_t)nn * K + k0 + lx] = f2bf(tile[lx * 33 + ly + i * 8]);
        }
    }
}

// ---------------------------------------------------------------------------
// RMSNorm -> bf16 (layer 1 only)
// ---------------------------------------------------------------------------
__global__ __launch_bounds__(256) void rmsnorm_kernel(
    const float* __restrict__ x, const float* __restrict__ w,
    short* __restrict__ out)
{
    int row = blockIdx.x;
    const float* xr = x + (size_t)row * DM;
    float s = 0.f;
    for (int i = threadIdx.x; i < DM; i += 256) { float v = xr[i]; s += v * v; }
    #pragma unroll
    for (int off = 32; off > 0; off >>= 1) s += __shfl_down(s, off, 64);
    __shared__ float ws[4];
    int wave = threadIdx.x >> 6, lane = threadIdx.x & 63;
    if (lane == 0) ws[wave] = s;
    __syncthreads();
    float tot = ws[0] + ws[1] + ws[2] + ws[3];
    float rs = rsqrtf(tot / (float)DM + 1e-5f);
    for (int i = threadIdx.x; i < DM; i += 256)
        out[(size_t)row * DM + i] = f2bf(xr[i] * rs * w[i]);
}

// ---------------------------------------------------------------------------
// in_proj bf16 MFMA GEMM: 128x128 tiles; epilogue stores bf16 split:
// cols [0,DI) -> xcz_bf (conv input), cols [DI,2*DI) -> res_bf (gate).
// Tile cols never straddle the halves (128 | 1536).
// ---------------------------------------------------------------------------
__global__ __launch_bounds__(256) void gemm_inproj(
    const short* __restrict__ A, const short* __restrict__ Bt,
    short* __restrict__ xcz_bf, short* __restrict__ res_bf, int M, int N, int K)
{
    __shared__ short As[128 * 32];
    __shared__ short Bs[128 * 32];
    int tid = threadIdx.x, lane = tid & 63, w = tid >> 6;
    int wr = w >> 1, wc = w & 1;
    int brow = blockIdx.y * 128, bcol = blockIdx.x * 128;

    f32x4 acc[4][4] = {};

    for (int k0 = 0; k0 < K; k0 += 32) {
        #pragma unroll
        for (int i = 0; i < 2; i++) {
            int c = tid + i * 256;
            int r = c >> 2, q = c & 3;
            const short* ga = A  + (size_t)(brow + r) * K + k0 + q * 8;
            const short* gb = Bt + (size_t)(bcol + r) * K + k0 + q * 8;
            __builtin_amdgcn_global_load_lds(
                (const __attribute__((address_space(1))) void*)ga,
                (__attribute__((address_space(3))) void*)&As[r * 32 + q * 8],
                16, 0, 0);
            __builtin_amdgcn_global_load_lds(
                (const __attribute__((address_space(1))) void*)gb,
                (__attribute__((address_space(3))) void*)&Bs[r * 32 + q * 8],
                16, 0, 0);
        }
        __syncthreads();

        bf16x8 af[4], bfv[4];
        int kh = (lane >> 4) * 8;
        int ml = lane & 15;
        #pragma unroll
        for (int t = 0; t < 4; t++) {
            af[t]  = *(const bf16x8*)&As[(wr * 64 + t * 16 + ml) * 32 + kh];
            bfv[t] = *(const bf16x8*)&Bs[(wc * 64 + t * 16 + ml) * 32 + kh];
        }
        #pragma unroll
        for (int mt = 0; mt < 4; mt++)
            #pragma unroll
            for (int nt = 0; nt < 4; nt++)
                acc[mt][nt] = __builtin_amdgcn_mfma_f32_16x16x32_bf16(
                    af[mt], bfv[nt], acc[mt][nt], 0, 0, 0);
        __syncthreads();
    }

    // split bf16 store (block-uniform half selection)
    short* dst  = (bcol < DI) ? xcz_bf : res_bf;
    int    cofs = (bcol < DI) ? bcol : (bcol - DI);
    int r0 = (lane >> 4) * 4, c0 = lane & 15;
    #pragma unroll
    for (int mt = 0; mt < 4; mt++)
        #pragma unroll
        for (int nt = 0; nt < 4; nt++)
            #pragma unroll
            for (int reg = 0; reg < 4; reg++) {
                int row = brow + wr * 64 + mt * 16 + r0 + reg;
                int col = cofs + wc * 64 + nt * 16 + c0;
                dst[(size_t)row * DI + col] = f2bf(acc[mt][nt][reg]);
            }
}

// ---------------------------------------------------------------------------
// out_proj: 128x64 tiles, C += A@Bt^T (fp32 accumulate into residual x)
// ---------------------------------------------------------------------------
__global__ __launch_bounds__(256) void gemm_bf16_bt_n64(
    const short* __restrict__ A, const short* __restrict__ Bt,
    float* __restrict__ C, int M, int N, int K)
{
    __shared__ short As[128 * 32];
    __shared__ short Bs[64 * 32];
    int tid = threadIdx.x, lane = tid & 63, w = tid >> 6;
    int brow = blockIdx.y * 128, bcol = blockIdx.x * 64;

    f32x4 acc[2][4] = {};

    for (int k0 = 0; k0 < K; k0 += 32) {
        #pragma unroll
        for (int i = 0; i < 2; i++) {
            int c = tid + i * 256;
            int r = c >> 2, q = c & 3;
            const short* ga = A + (size_t)(brow + r) * K + k0 + q * 8;
            __builtin_amdgcn_global_load_lds(
                (const __attribute__((address_space(1))) void*)ga,
                (__attribute__((address_space(3))) void*)&As[r * 32 + q * 8],
                16, 0, 0);
        }
        {
            int r = tid >> 2, q = tid & 3;
            const short* gb = Bt + (size_t)(bcol + r) * K + k0 + q * 8;
            __builtin_amdgcn_global_load_lds(
                (const __attribute__((address_space(1))) void*)gb,
                (__attribute__((address_space(3))) void*)&Bs[r * 32 + q * 8],
                16, 0, 0);
        }
        __syncthreads();

        bf16x8 af[2], bfv[4];
        int kh = (lane >> 4) * 8;
        int ml = lane & 15;
        #pragma unroll
        for (int mt = 0; mt < 2; mt++)
            af[mt] = *(const bf16x8*)&As[(w * 32 + mt * 16 + ml) * 32 + kh];
        #pragma unroll
        for (int nt = 0; nt < 4; nt++)
            bfv[nt] = *(const bf16x8*)&Bs[(nt * 16 + ml) * 32 + kh];
        #pragma unroll
        for (int mt = 0; mt < 2; mt++)
            #pragma unroll
            for (int nt = 0; nt < 4; nt++)
                acc[mt][nt] = __builtin_amdgcn_mfma_f32_16x16x32_bf16(
                    af[mt], bfv[nt], acc[mt][nt], 0, 0, 0);
        __syncthreads();
    }

    int r0 = (lane >> 4) * 4, c0 = lane & 15;
    #pragma unroll
    for (int mt = 0; mt < 2; mt++)
        #pragma unroll
        for (int nt = 0; nt < 4; nt++)
            #pragma unroll
            for (int reg = 0; reg < 4; reg++) {
                int row = brow + w * 32 + mt * 16 + r0 + reg;
                int col = bcol + nt * 16 + c0;
                C[(size_t)row * N + col] += acc[mt][nt][reg];
            }
}

// ---------------------------------------------------------------------------
// Causal depthwise conv (width 4) + bias + SiLU; bf16 in (compact), bf16 out.
// Streaming grid (12288 blocks) — max TLP (r7's fused version regressed).
// ---------------------------------------------------------------------------
__global__ __launch_bounds__(256) void conv_silu_kernel(
    const short* __restrict__ xcz_bf, const float* __restrict__ w,
    const float* __restrict__ b, short* __restrict__ xr_bf)
{
    int idx = blockIdx.x * 256 + threadIdx.x;
    if (idx >= L_SEQ * DI) return;
    int l = idx / DI, c = idx % DI;
    float4 wc = ((const float4*)w)[c];
    const short* col = xcz_bf + c;
    float acc = b[c];
    if (l >= 3) {
        acc += wc.x * bf2f(col[(size_t)(l - 3) * DI])
             + wc.y * bf2f(col[(size_t)(l - 2) * DI])
             + wc.z * bf2f(col[(size_t)(l - 1) * DI])
             + wc.w * bf2f(col[(size_t)l * DI]);
    } else {
        const float wv[4] = {wc.x, wc.y, wc.z, wc.w};
        for (int k = 0; k < 4; k++) {
            int ls = l - 3 + k;
            if (ls >= 0) acc += wv[k] * bf2f(col[(size_t)ls * DI]);
        }
    }
    xr_bf[idx] = f2bf(silu_f(acc));
}

// ---------------------------------------------------------------------------
// x_proj split-K MFMA: part[s][L][80] (r5 global-read version)
// ---------------------------------------------------------------------------
__global__ __launch_bounds__(256) void xproj_splitk(
    const short* __restrict__ xr_bf,
    const short* __restrict__ xpw_t,
    float* __restrict__ part)
{
    int w = threadIdx.x >> 6, lane = threadIdx.x & 63;
    int r0 = blockIdx.x * 64 + w * 16;
    int k0 = blockIdx.y * XPK;
    int ml = lane & 15, kh = (lane >> 4) * 8;

    f32x4 acc[5] = {};
    for (int ks = 0; ks < XPK; ks += 32) {
        bf16x8 a = *(const bf16x8*)&xr_bf[(size_t)(r0 + ml) * DI + k0 + ks + kh];
        #pragma unroll
        for (int t = 0; t < 5; t++) {
            bf16x8 b = *(const bf16x8*)&xpw_t[(size_t)(t * 16 + ml) * DI + k0 + ks + kh];
            acc[t] = __builtin_amdgcn_mfma_f32_16x16x32_bf16(a, b, acc[t], 0, 0, 0);
        }
    }
    float* po = part + (size_t)blockIdx.y * L_SEQ * XDW;
    int r_base = r0 + (lane >> 4) * 4;
    #pragma unroll
    for (int t = 0; t < 5; t++)
        #pragma unroll
        for (int reg = 0; reg < 4; reg++)
            po[(size_t)(r_base + reg) * XDW + t * 16 + ml] = acc[t][reg];
}

// ---------------------------------------------------------------------------
// dt_proj fused: reduce xpart partials + fp32 GEMM(K=48) + softplus -> delta.
// Blocks with blockIdx.x%24==0 also reduce B/C cols -> xdbl_bc[L][32].
// ---------------------------------------------------------------------------
__global__ __launch_bounds__(256) void dtproj_fused(
    const float* __restrict__ xpart, const float* __restrict__ dpw,
    const float* __restrict__ dpb, float* __restrict__ delta,
    float* __restrict__ xdbl_bc)
{
    __shared__ __align__(16) float As_f[16 * 68];
    __shared__ __align__(16) float Bs_f[16 * 68];
    int tid = threadIdx.x;
    int ty = tid >> 4, tx = tid & 15;
    int t = blockIdx.x;
    int bcol = (t % 24) * 64;
    int brow = (t / 24) * 64;

    float acc[4][4] = {};
    for (int k0 = 0; k0 < 48; k0 += 16) {
        __syncthreads();
        #pragma unroll
        for (int i = 0; i < 4; i++) {
            int idx = tid + i * 256;
            int m = idx >> 4, k = idx & 15;
            float s = 0.f;
            #pragma unroll
            for (int p = 0; p < XPS; p++)
                s += xpart[((size_t)p * L_SEQ + brow + m) * XDW + k0 + k];
            As_f[k * 68 + m] = s;
        }
        #pragma unroll
        for (int i = 0; i < 4; i++) {
            int idx = tid + i * 256;
            int k = idx >> 6, n = idx & 63;
            Bs_f[k * 68 + n] = dpw[(size_t)(k0 + k) * DI + bcol + n];
        }
        __syncthreads();
        #pragma unroll
        for (int k = 0; k < 16; k++) {
            float4 av = *(const float4*)&As_f[k * 68 + ty * 4];
            float4 bv = *(const float4*)&Bs_f[k * 68 + tx * 4];
            float a4[4] = {av.x, av.y, av.z, av.w};
            float b4[4] = {bv.x, bv.y, bv.z, bv.w};
            #pragma unroll
            for (int i = 0; i < 4; i++)
                #pragma unroll
                for (int jj = 0; jj < 4; jj++)
                    acc[i][jj] += a4[i] * b4[jj];
        }
    }
    #pragma unroll
    for (int i = 0; i < 4; i++) {
        int row = brow + ty * 4 + i;
        #pragma unroll
        for (int jj = 0; jj < 4; jj++) {
            int col = bcol + tx * 4 + jj;
            float v = acc[i][jj] + dpb[col];
            delta[(size_t)row * DI + col] = (v > 20.f) ? v : log1pf(__expf(v));
        }
    }
    if (t % 24 == 0) {
        for (int e = tid; e < 64 * 32; e += 256) {
            int r = e >> 5, cc = e & 31;
            float s = 0.f;
            #pragma unroll
            for (int p = 0; p < XPS; p++)
                s += xpart[((size_t)p * L_SEQ + brow + r) * XDW + DTR + cc];
            xdbl_bc[(size_t)(brow + r) * 32 + cc] = s;
        }
    }
}

// ---------------------------------------------------------------------------
// Scan pass A
// ---------------------------------------------------------------------------
__global__ __launch_bounds__(256) void scan_passA(
    const float* __restrict__ delta, const short* __restrict__ xr_bf,
    const float* __restrict__ xdbl_bc, const float* __restrict__ al,
    float* __restrict__ aprod, float* __restrict__ hfin)
{
    int d = blockIdx.x * 256 + threadIdx.x;
    int c = blockIdx.y;

    float Aloc[DST], h[DST], P[DST];
    #pragma unroll
    for (int n4 = 0; n4 < DST; n4 += 4) {
        float4 alv = *(const float4*)&al[(size_t)d * DST + n4];
        Aloc[n4 + 0] = -__expf(alv.x); Aloc[n4 + 1] = -__expf(alv.y);
        Aloc[n4 + 2] = -__expf(alv.z); Aloc[n4 + 3] = -__expf(alv.w);
    }
    #pragma unroll
    for (int n = 0; n < DST; n++) { h[n] = 0.f; P[n] = 1.f; }

    int l0 = c * LC;
    for (int l = l0; l < l0 + LC; l++) {
        float dl = delta[(size_t)l * DI + d];
        float ul = bf2f(xr_bf[(size_t)l * DI + d]);
        float du = dl * ul;
        float Bv[DST];
        const float4* B4 = (const float4*)(xdbl_bc + (size_t)l * 32);
        *(float4*)&Bv[0] = B4[0]; *(float4*)&Bv[4]  = B4[1];
        *(float4*)&Bv[8] = B4[2]; *(float4*)&Bv[12] = B4[3];
        #pragma unroll
        for (int n = 0; n < DST; n++) {
            float da = __expf(dl * Aloc[n]);
            h[n] = h[n] * da + du * Bv[n];
            P[n] *= da;
        }
    }
    size_t base = ((size_t)c * DI + d) * DST;
    #pragma unroll
    for (int n = 0; n < DST; n += 4) {
        *(float4*)&aprod[base + n] = *(float4*)&P[n];
        *(float4*)&hfin[base + n]  = *(float4*)&h[n];
    }
}

// ---------------------------------------------------------------------------
// Pass B: sequential carry over chunks (coalesced)
// ---------------------------------------------------------------------------
__global__ __launch_bounds__(256) void scan_passB(
    const float* __restrict__ aprod, const float* __restrict__ hfin,
    float* __restrict__ hin)
{
    int idx = blockIdx.x * 256 + threadIdx.x;
    if (idx >= DI * DST) return;
    float cur = 0.f;
    for (int c = 0; c < NCH; c++) {
        size_t o = (size_t)c * DI * DST + idx;
        hin[o] = cur;
        cur = hfin[o] + aprod[o] * cur;
    }
}

// ---------------------------------------------------------------------------
// Pass C: replay with carry; fuse y, D, gating (res_bf) -> y2_bf
// ---------------------------------------------------------------------------
__global__ __launch_bounds__(256) void scan_passC(
    const float* __restrict__ delta, const short* __restrict__ xr_bf,
    const float* __restrict__ xdbl_bc, const float* __restrict__ al,
    const float* __restrict__ dpp, const float* __restrict__ hin,
    const short* __restrict__ res_bf, short* __restrict__ y2)
{
    int d = blockIdx.x * 256 + threadIdx.x;
    int c = blockIdx.y;

    float Aloc[DST], h[DST];
    #pragma unroll
    for (int n4 = 0; n4 < DST; n4 += 4) {
        float4 alv = *(const float4*)&al[(size_t)d * DST + n4];
        Aloc[n4 + 0] = -__expf(alv.x); Aloc[n4 + 1] = -__expf(alv.y);
        Aloc[n4 + 2] = -__expf(alv.z); Aloc[n4 + 3] = -__expf(alv.w);
    }
    size_t base = ((size_t)c * DI + d) * DST;
    #pragma unroll
    for (int n = 0; n < DST; n += 4)
        *(float4*)&h[n] = *(const float4*)&hin[base + n];
    float Dd = dpp[d];

    int l0 = c * LC;
    for (int l = l0; l < l0 + LC; l++) {
        float dl = delta[(size_t)l * DI + d];
        float ul = bf2f(xr_bf[(size_t)l * DI + d]);
        float du = dl * ul;
        float Bv[DST], Cv[DST];
        const float4* B4 = (const float4*)(xdbl_bc + (size_t)l * 32);
        const float4* C4 = (const float4*)(xdbl_bc + (size_t)l * 32 + 16);
        *(float4*)&Bv[0] = B4[0]; *(float4*)&Bv[4]  = B4[1];
        *(float4*)&Bv[8] = B4[2]; *(float4*)&Bv[12] = B4[3];
        *(float4*)&Cv[0] = C4[0]; *(float4*)&Cv[4]  = C4[1];
        *(float4*)&Cv[8] = C4[2]; *(float4*)&Cv[12] = C4[3];
        float y = 0.f;
        #pragma unroll
        for (int n = 0; n < DST; n++) {
            float da = __expf(dl * Aloc[n]);
            h[n] = h[n] * da + du * Bv[n];
            y += h[n] * Cv[n];
        }
        y += ul * Dd;
        float r = bf2f(res_bf[(size_t)l * DI + d]);
        y2[(size_t)l * DI + d] = f2bf(y * silu_f(r));
    }
}

// ---------------------------------------------------------------------------
// Host launch: 18 dispatches
// ---------------------------------------------------------------------------
extern "C" void kernel_launch(void* const* d_in, const int* in_sizes, int n_in,
                              void* d_out, int out_size, void* d_ws, size_t ws_size,
                              hipStream_t stream)
{
    const int*   ids       = (const int*)d_in[0];
    const float* emb       = (const float*)d_in[1];
    const float* norm_w    = (const float*)d_in[2];
    const float* in_proj_w = (const float*)d_in[3];
    const float* conv_w    = (const float*)d_in[4];
    const float* conv_b    = (const float*)d_in[5];
    const float* x_proj_w  = (const float*)d_in[6];
    const float* dt_proj_w = (const float*)d_in[7];
    const float* dt_proj_b = (const float*)d_in[8];
    const float* A_log     = (const float*)d_in[9];
    const float* Dp        = (const float*)d_in[10];
    const float* out_proj_w= (const float*)d_in[11];

    float* x = (float*)d_out;

    char* wsb = (char*)d_ws;
    auto alloc_f = [&](size_t n) { float* p = (float*)wsb; wsb += n * 4; return p; };
    auto alloc_s = [&](size_t n) { short* p = (short*)wsb; wsb += ((n * 2 + 15) & ~15ull); return p; };

    float* delta   = alloc_f((size_t)L_SEQ * DI);
    float* xpart   = alloc_f((size_t)XPS * L_SEQ * XDW);
    float* xdbl_bc = alloc_f((size_t)L_SEQ * 32);
    float* aprod   = alloc_f((size_t)NCH * DI * DST);
    float* hfin    = alloc_f((size_t)NCH * DI * DST);
    float* hin     = alloc_f((size_t)NCH * DI * DST);
    short* xcz_bf  = alloc_s((size_t)L_SEQ * DI);
    short* res_bf  = alloc_s((size_t)L_SEQ * DI);
    short* xn_bf   = alloc_s((size_t)L_SEQ * DM);
    short* y2_bf   = alloc_s((size_t)L_SEQ * DI);
    short* xr_bf   = alloc_s((size_t)L_SEQ * DI);
    short* ipw_t   = alloc_s((size_t)2 * 2 * DI * DM);
    short* opw_t   = alloc_s((size_t)2 * DM * DI);
    short* xpw_t   = alloc_s((size_t)2 * XDW * DI);

    // 1 dispatch: embed + rmsnorm(L0) + all weight transposes
    prep_kernel<<<L_SEQ, 256, 0, stream>>>(
        ids, emb, norm_w, in_proj_w, out_proj_w, x_proj_w,
        x, xn_bf, ipw_t, opw_t, xpw_t);

    for (int layer = 0; layer < 2; layer++) {
        const float* nw   = norm_w    + (size_t)layer * DM;
        const float* cw   = conv_w    + (size_t)layer * DI * 4;
        const float* cb   = conv_b    + (size_t)layer * DI;
        const float* dpw  = dt_proj_w + (size_t)layer * DTR * DI;
        const float* dpb  = dt_proj_b + (size_t)layer * DI;
        const float* al   = A_log     + (size_t)layer * DI * DST;
        const float* dpp  = Dp        + (size_t)layer * DI;
        const short* ipwt = ipw_t + (size_t)layer * 2 * DI * DM;
        const short* opwt = opw_t + (size_t)layer * DM * DI;
        const short* xpwt = xpw_t + (size_t)layer * XDW * DI;

        if (layer == 1)
            rmsnorm_kernel<<<L_SEQ, 256, 0, stream>>>(x, nw, xn_bf);

        gemm_inproj<<<dim3(2 * DI / 128, L_SEQ / 128), 256, 0, stream>>>(
            xn_bf, ipwt, xcz_bf, res_bf, L_SEQ, 2 * DI, DM);

        conv_silu_kernel<<<(L_SEQ * DI) / 256, 256, 0, stream>>>(
            xcz_bf, cw, cb, xr_bf);

        xproj_splitk<<<dim3(L_SEQ / 64, XPS), 256, 0, stream>>>(xr_bf, xpwt, xpart);

        dtproj_fused<<<768, 256, 0, stream>>>(xpart, dpw, dpb, delta, xdbl_bc);

        scan_passA<<<dim3(DI / 256, NCH), 256, 0, stream>>>(
            delta, xr_bf, xdbl_bc, al, aprod, hfin);
        scan_passB<<<(DI * DST) / 256, 256, 0, stream>>>(aprod, hfin, hin);
        scan_passC<<<dim3(DI / 256, NCH), 256, 0, stream>>>(
            delta, xr_bf, xdbl_bc, al, dpp, hin, res_bf, y2_bf);

        gemm_bf16_bt_n64<<<dim3(DM / 64, L_SEQ / 128), 256, 0, stream>>>(
            y2_bf, opwt, x, L_SEQ, DM, DI);
    }
}